// Round 7
// baseline (1328.717 us; speedup 1.0000x reference)
//
#include <hip/hip_runtime.h>

#define T_ 4
#define B_ 64
#define D_ 512
#define V_ 256

// ---- workspace byte offsets ----
// x splits, frag-linear: [bt 256][it 16][vg 16][lane 64][e 8] u16 (67.1 MB each)
#define XSH   0ull
#define XSM   67108864ull
#define XSL   134217728ull
// gate*k spikes, binary bf16, same frag-linear layout (67.1 MB)
#define OUTBT 201326592ull
// W splits frag-linear: (mat*3+s) arrays: [head 4][it 16][ip 8][lane 64][e 8]
#define WT    268435456ull
#define BNOF  273154048ull     // 6x512 floats

typedef unsigned short u16;
typedef __attribute__((ext_vector_type(8))) __bf16 bf16x8;
typedef __attribute__((ext_vector_type(4))) float f32x4;
typedef __attribute__((ext_vector_type(8))) unsigned short u16x8;
typedef __attribute__((ext_vector_type(4))) unsigned short u16x4;

__device__ __forceinline__ u16 f2bf(float f) {
    unsigned u = __float_as_uint(f);
    return (u16)((u + 0x7FFFu + ((u >> 16) & 1u)) >> 16);
}
__device__ __forceinline__ float bf2f(u16 h) {
    return __uint_as_float(((unsigned)h) << 16);
}

// ---------------------------------------------------------------------------
// prep: W 3-way bf16 splits in frag-linear layout + BN constants.
// ---------------------------------------------------------------------------
__global__ __launch_bounds__(256) void k_prep2(
    const float* __restrict__ Wq, const float* __restrict__ Wk, const float* __restrict__ Wp,
    const float* __restrict__ qg, const float* __restrict__ qb,
    const float* __restrict__ qm, const float* __restrict__ qv,
    const float* __restrict__ kg, const float* __restrict__ kb,
    const float* __restrict__ km, const float* __restrict__ kv,
    const float* __restrict__ pg, const float* __restrict__ pb,
    const float* __restrict__ pm, const float* __restrict__ pv,
    char* __restrict__ ws)
{
    const int g = blockIdx.x * 256 + threadIdx.x;   // [0, 98304)
    const int mat = g >> 15;
    const int r = g & 32767;
    const int lane = r & 63;
    const int q = r >> 6;            // (head*16+it)*8+ip
    const int ip = q & 7;
    const int q2 = q >> 3;
    const int it = q2 & 15;
    const int head = q2 >> 4;
    const int row = head * 128 + ip * 16 + (lane & 15);
    const int kcol = it * 32 + (lane >> 4) * 8;
    const float* W = (mat == 0) ? Wq : (mat == 1 ? Wk : Wp);

    u16x8 h8, m8, l8;
#pragma unroll
    for (int e = 0; e < 8; ++e) {
        const float f = W[row * 512 + kcol + e];
        const u16 h = f2bf(f);          const float fh = bf2f(h);
        const u16 m = f2bf(f - fh);     const float fm = bf2f(m);
        const u16 l = f2bf(f - fh - fm);
        h8[e] = h; m8[e] = m; l8[e] = l;
    }
    u16* wt = (u16*)(ws + WT);
    const size_t o = (size_t)r * 8;
    *(u16x8*)(wt + (size_t)(mat * 3 + 0) * 262144 + o) = h8;
    *(u16x8*)(wt + (size_t)(mat * 3 + 1) * 262144 + o) = m8;
    *(u16x8*)(wt + (size_t)(mat * 3 + 2) * 262144 + o) = l8;

    if (g < 512) {
        float* bn = (float*)(ws + BNOF);
        float iv;
        iv = qg[g] * (1.0f / sqrtf(qv[g] + 1e-5f)); bn[g]        = iv; bn[512  + g] = qb[g] - qm[g] * iv;
        iv = kg[g] * (1.0f / sqrtf(kv[g] + 1e-5f)); bn[1024 + g] = iv; bn[1536 + g] = kb[g] - km[g] * iv;
        iv = pg[g] * (1.0f / sqrtf(pv[g] + 1e-5f)); bn[2048 + g] = iv; bn[2560 + g] = pb[g] - pm[g] * iv;
    }
}

// ---------------------------------------------------------------------------
// split_x: x (t,b,d,v) fp32 -> 3-way bf16 splits in frag-linear layout.
// ---------------------------------------------------------------------------
__global__ __launch_bounds__(256) void k_split_x2(
    const float* __restrict__ x, char* __restrict__ ws)
{
    const int bt = blockIdx.x >> 4;
    const int it = blockIdx.x & 15;
    const int tid = threadIdx.x;
#pragma unroll
    for (int r2 = 0; r2 < 4; ++r2) {
        const int slot = r2 * 256 + tid;       // 0..1023 = vg*64 + lane
        const int vg = slot >> 6;
        const int ll = slot & 63;
        const int v  = vg * 16 + (ll & 15);
        const int d0 = it * 32 + (ll >> 4) * 8;
        u16x8 h8, m8, l8;
#pragma unroll
        for (int e = 0; e < 8; ++e) {
            const float f = x[(size_t)bt * 131072 + (size_t)(d0 + e) * 256 + v];
            const u16 h = f2bf(f);          const float fh = bf2f(h);
            const u16 m = f2bf(f - fh);     const float fm = bf2f(m);
            const u16 lo = f2bf(f - fh - fm);
            h8[e] = h; m8[e] = m; l8[e] = lo;
        }
        const size_t o = (size_t)bt * 262144ull + (size_t)it * 16384ull
                       + (size_t)vg * 1024ull + (size_t)ll * 16ull;
        *(u16x8*)(ws + XSH + o) = h8;
        *(u16x8*)(ws + XSM + o) = m8;
        *(u16x8*)(ws + XSL + o) = l8;
    }
}

// ---------------------------------------------------------------------------
// Fused q+k, barrier-free K-loop, frag-linear operands direct from global.
// Block = (b, head), XCD-swizzled: b = bid&63 so all 4 heads of a b share an
// XCD (bid ≡ b mod 8) -> B-rows L2-shared instead of 4x HBM fetch.
// ---------------------------------------------------------------------------
__global__ __launch_bounds__(512, 4) void k_qk2(char* __restrict__ ws)
{
    __shared__ u16 tile[32768];      // 64KB: k-spike out tile, frag-linear
    __shared__ float qs[2][256];
    __shared__ float gatef[4][256];

    const int tid  = threadIdx.x;
    const int lane = tid & 63;
    const int wave = tid >> 6;       // 0..7
    const int wr = wave >> 2;        // 0..1  (o half)
    const int wc = wave & 3;         // 0..3  (v quarter)
    const int quad = lane >> 4;
    const int l15  = lane & 15;

    const int b    = blockIdx.x & 63;   // XCD-swizzle: same-b blocks same XCD
    const int head = blockIdx.x >> 6;

    constexpr int PA[6] = {0, 0, 1, 1, 0, 2};
    constexpr int PB[6] = {0, 1, 0, 1, 2, 0};

    float gstate = 0.f;

    for (int ph = 0; ph < 2; ++ph) {
        const size_t abase = WT + (size_t)ph * 3ull * 524288ull
                           + (size_t)head * 131072ull
                           + (size_t)wr * 4096ull + (size_t)lane * 16ull;
        const float* bn = (const float*)(ws + BNOF + (size_t)ph * 4096);

        f32x4 st[4][4];
#pragma unroll
        for (int i = 0; i < 4; ++i)
#pragma unroll
            for (int j = 0; j < 4; ++j) st[i][j] = (f32x4){0.f, 0.f, 0.f, 0.f};

        for (int t = 0; t < 4; ++t) {
            const int bt = t * 64 + b;
            const size_t bbase = (size_t)bt * 262144ull
                               + (size_t)(wc * 4) * 1024ull + (size_t)lane * 16ull;
            f32x4 acc[4][4];
#pragma unroll
            for (int i = 0; i < 4; ++i)
#pragma unroll
                for (int j = 0; j < 4; ++j) acc[i][j] = (f32x4){0.f, 0.f, 0.f, 0.f};

#pragma unroll 4
            for (int it = 0; it < 16; ++it) {
                bf16x8 afr[3][4];
#pragma unroll
                for (int s = 0; s < 3; ++s)
#pragma unroll
                    for (int i = 0; i < 4; ++i)
                        afr[s][i] = *(const bf16x8*)(ws + abase + (size_t)s * 524288ull
                                      + (size_t)it * 8192ull + (size_t)i * 1024ull);
#pragma unroll
                for (int j = 0; j < 4; ++j) {
                    bf16x8 bfr[3];
#pragma unroll
                    for (int s = 0; s < 3; ++s)
                        bfr[s] = *(const bf16x8*)(ws + (size_t)s * 67108864ull + bbase
                                   + (size_t)it * 16384ull + (size_t)j * 1024ull);
#pragma unroll
                    for (int i = 0; i < 4; ++i)
#pragma unroll
                        for (int p = 0; p < 6; ++p)
                            acc[i][j] = __builtin_amdgcn_mfma_f32_16x16x32_bf16(
                                afr[PA[p]][i], bfr[PB[p]], acc[i][j], 0, 0, 0);
                }
            }

            if (ph == 0) {
                // ---- phase Q epilogue: BN + LIF + per-column spike sums ----
                float qp[4] = {0.f, 0.f, 0.f, 0.f};
#pragma unroll
                for (int i = 0; i < 4; ++i) {
                    const int ob = head * 128 + wr * 64 + i * 16 + quad * 4;
                    const f32x4 inv = *(const f32x4*)(bn + ob);
                    const f32x4 add = *(const f32x4*)(bn + 512 + ob);
#pragma unroll
                    for (int j = 0; j < 4; ++j)
#pragma unroll
                        for (int r = 0; r < 4; ++r) {
                            const float y = acc[i][j][r] * inv[r] + add[r];
                            float v = (st[i][j][r] + y) * 0.5f;
                            const float s = (v >= 1.0f) ? 1.f : 0.f;
                            st[i][j][r] = (v >= 1.0f) ? 0.f : v;
                            qp[j] += s;
                        }
                }
#pragma unroll
                for (int j = 0; j < 4; ++j) {
                    qp[j] += __shfl_xor(qp[j], 16, 64);
                    qp[j] += __shfl_xor(qp[j], 32, 64);
                }
                if (quad == 0) {
#pragma unroll
                    for (int j = 0; j < 4; ++j)
                        qs[wr][wc * 64 + j * 16 + l15] = qp[j];
                }
                __syncthreads();
                if (tid < 256) {
                    const float qsum = qs[0][tid] + qs[1][tid];
                    gstate = (gstate + qsum) * 0.5f;
                    const float gt = (gstate >= 0.5f) ? 1.f : 0.f;
                    gstate = (gstate >= 0.5f) ? 0.f : gstate;
                    gatef[t][tid] = gt;
                }
                __syncthreads();
            } else {
                // ---- phase K epilogue: BN + LIF + gate -> frag-linear tile ----
#pragma unroll
                for (int i = 0; i < 4; ++i) {
                    const int ob = head * 128 + wr * 64 + i * 16 + quad * 4;
                    const f32x4 inv = *(const f32x4*)(bn + ob);
                    const f32x4 add = *(const f32x4*)(bn + 512 + ob);
                    const int itL = wr * 2 + (i >> 1);
                    const int ls  = ((i & 1) * 2 + (quad >> 1)) * 16 + l15;
                    const int e0  = (quad & 1) * 4;
#pragma unroll
                    for (int j = 0; j < 4; ++j) {
                        const int col = wc * 64 + j * 16 + l15;
                        const float gt = gatef[t][col];
                        u16x4 w;
#pragma unroll
                        for (int r = 0; r < 4; ++r) {
                            const float y = acc[i][j][r] * inv[r] + add[r];
                            float v = (st[i][j][r] + y) * 0.5f;
                            const float s = (v >= 1.0f) ? 1.f : 0.f;
                            st[i][j][r] = (v >= 1.0f) ? 0.f : v;
                            w[r] = (s * gt != 0.f) ? (u16)0x3F80 : (u16)0;
                        }
                        *(u16x4*)&tile[(size_t)((itL * 16 + wc * 4 + j) * 64 + ls) * 8 + e0] = w;
                    }
                }
                __syncthreads();
                const size_t dst = OUTBT + ((size_t)bt * 16ull + (size_t)head * 4ull) * 16384ull;
#pragma unroll
                for (int c = 0; c < 8; ++c) {
                    const int idx = c * 512 + tid;   // float4 units, 0..4095
                    *(float4*)(ws + dst + (size_t)idx * 16) = *(const float4*)&tile[(size_t)idx * 8];
                }
                __syncthreads();
            }
        }
    }
}

// ---------------------------------------------------------------------------
// Fused p, barrier-free: out2 = LIF(bn_p(Wp @ out)). Block = (b, ot),
// XCD-swizzled like k_qk2.
// ---------------------------------------------------------------------------
__global__ __launch_bounds__(512, 4) void k_p2(char* __restrict__ ws,
                                               float* __restrict__ out2)
{
    const int tid  = threadIdx.x;
    const int lane = tid & 63;
    const int wave = tid >> 6;
    const int wr = wave >> 2;
    const int wc = wave & 3;
    const int quad = lane >> 4;
    const int l15  = lane & 15;

    const int b  = blockIdx.x & 63;   // XCD-swizzle
    const int ot = blockIdx.x >> 6;

    const size_t abase = WT + 6ull * 524288ull + (size_t)ot * 131072ull
                       + (size_t)wr * 4096ull + (size_t)lane * 16ull;
    const float* bn = (const float*)(ws + BNOF + 8192);

    f32x4 st[4][4];
#pragma unroll
    for (int i = 0; i < 4; ++i)
#pragma unroll
        for (int j = 0; j < 4; ++j) st[i][j] = (f32x4){0.f, 0.f, 0.f, 0.f};

    for (int t = 0; t < 4; ++t) {
        const int bt = t * 64 + b;
        const size_t bbase = OUTBT + (size_t)bt * 262144ull
                           + (size_t)(wc * 4) * 1024ull + (size_t)lane * 16ull;
        f32x4 acc[4][4];
#pragma unroll
        for (int i = 0; i < 4; ++i)
#pragma unroll
            for (int j = 0; j < 4; ++j) acc[i][j] = (f32x4){0.f, 0.f, 0.f, 0.f};

#pragma unroll 4
        for (int it = 0; it < 16; ++it) {
            bf16x8 afr[3][4];
#pragma unroll
            for (int s = 0; s < 3; ++s)
#pragma unroll
                for (int i = 0; i < 4; ++i)
                    afr[s][i] = *(const bf16x8*)(ws + abase + (size_t)s * 524288ull
                                  + (size_t)it * 8192ull + (size_t)i * 1024ull);
#pragma unroll
            for (int j = 0; j < 4; ++j) {
                const bf16x8 bfr = *(const bf16x8*)(ws + bbase
                                     + (size_t)it * 16384ull + (size_t)j * 1024ull);
#pragma unroll
                for (int i = 0; i < 4; ++i)
#pragma unroll
                    for (int p = 0; p < 3; ++p)
                        acc[i][j] = __builtin_amdgcn_mfma_f32_16x16x32_bf16(
                            afr[p][i], bfr, acc[i][j], 0, 0, 0);
            }
        }

        // epilogue: BN + LIF step t, write spikes (T,B,D,V) fp32
#pragma unroll
        for (int i = 0; i < 4; ++i) {
            const int ob = ot * 128 + wr * 64 + i * 16 + quad * 4;
            const f32x4 inv = *(const f32x4*)(bn + ob);
            const f32x4 add = *(const f32x4*)(bn + 512 + ob);
#pragma unroll
            for (int j = 0; j < 4; ++j) {
                const int col = wc * 64 + j * 16 + l15;
#pragma unroll
                for (int r = 0; r < 4; ++r) {
                    const float y = acc[i][j][r] * inv[r] + add[r];
                    float v = (st[i][j][r] + y) * 0.5f;
                    const float s = (v >= 1.0f) ? 1.f : 0.f;
                    st[i][j][r] = (v >= 1.0f) ? 0.f : v;
                    out2[((size_t)(t * 64 + b) * 512 + ob + r) * 256 + col] = s;
                }
            }
        }
    }
}

// ---------------------------------------------------------------------------
extern "C" void kernel_launch(void* const* d_in, const int* in_sizes, int n_in,
                              void* d_out, int out_size, void* d_ws, size_t ws_size,
                              hipStream_t stream)
{
    const float* x  = (const float*)d_in[0];
    const float* Wq = (const float*)d_in[1];
    const float* qg = (const float*)d_in[2];
    const float* qb = (const float*)d_in[3];
    const float* qm = (const float*)d_in[4];
    const float* qv = (const float*)d_in[5];
    const float* Wk = (const float*)d_in[6];
    const float* kg = (const float*)d_in[7];
    const float* kb = (const float*)d_in[8];
    const float* km = (const float*)d_in[9];
    const float* kv = (const float*)d_in[10];
    const float* Wp = (const float*)d_in[11];
    const float* pg = (const float*)d_in[12];
    const float* pb = (const float*)d_in[13];
    const float* pm = (const float*)d_in[14];
    const float* pv = (const float*)d_in[15];

    char* ws = (char*)d_ws;

    k_prep2<<<384, 256, 0, stream>>>(Wq, Wk, Wp, qg, qb, qm, qv,
                                     kg, kb, km, kv, pg, pb, pm, pv, ws);

    k_split_x2<<<4096, 256, 0, stream>>>(x, ws);

    k_qk2<<<256, 512, 0, stream>>>(ws);

    k_p2<<<256, 512, 0, stream>>>(ws, (float*)d_out);
}